// Round 4
// baseline (932.207 us; speedup 1.0000x reference)
//
#include <hip/hip_runtime.h>

// ---------------------------------------------------------------------------
// MultiHeadAttention (fp32 I/O, bf16 MFMA compute):
//   LN -> {Q,K,V} proj -> softmax(QK^T/8 + pos, mask) -> attn (materialized,
//   fp32, part of d_out) -> PV -> out proj.
// B=4 H=8 S=2048 D=512 DK=64.  d_out = [out (B,S,D) | attn (B,H,S,S)] fp32.
//
// attn kernel uses SWAPPED QK^T (mfma(K,Q)) so each lane holds 4 consecutive
// keys of ONE q-row: P feeds the PV MFMA directly from registers (V stored
// k-permuted to match), attn stores are f32x4, and the P LDS round-trip that
// dominated rounds 0-3 is gone.
// ---------------------------------------------------------------------------

typedef __bf16 bf16;
typedef __attribute__((ext_vector_type(8))) __bf16 bfv8;   // 16 B MFMA frag
typedef __attribute__((ext_vector_type(4))) __bf16 bfv4;   // 8 B
typedef __attribute__((ext_vector_type(2))) __bf16 bfv2;   // 4 B
typedef __attribute__((ext_vector_type(4))) float  f32x4;  // MFMA acc / 16 B
typedef __attribute__((ext_vector_type(2))) float  f32x2;  // 8 B

static constexpr int Dm = 512, Hh = 8, Sq = 2048, Bb = 4;
static constexpr int BS = Bb * Sq;                 // 8192 rows

__device__ __forceinline__ f32x4 mfma16(bfv8 a, bfv8 b, f32x4 c) {
  return __builtin_amdgcn_mfma_f32_16x16x32_bf16(a, b, c, 0, 0, 0);
}

// ------- K0: posQ strip-tiled masked pos, key-minor interleave ---------------
// posQ[strip][j>>2][i&15][j&3]  (strip = i>>4), i.e. element (i,j) at
//   strip*32768 + (j>>2)*64 + (i&15)*4 + (j&3)
// In the attn kernel a lane (quad,r16) reads f32x4 at key0=c0+t*16+quad*4,
// row r16: base (c0/4+t*4+quad)*64 + r16*4 -> one 1-KB coalesced wave read.
__global__ __launch_bounds__(256) void posQ_kernel(
    const float* __restrict__ pos, const int* __restrict__ mask,
    float* __restrict__ posQ) {
  __shared__ float tile[32][33];
  int i0 = blockIdx.y * 32, j0 = blockIdx.x * 32;
  int tx = threadIdx.x & 31, ty = threadIdx.x >> 5;  // 32 x 8
#pragma unroll
  for (int rr = 0; rr < 32; rr += 8) {
    int i = i0 + ty + rr, j = j0 + tx;
    float pv = pos[(size_t)i * Sq + j];
    int   mv = mask[(size_t)i * Sq + j];
    tile[ty + rr][tx] = mv ? pv : -1e30f;   // tile[i_local][j_local]
  }
  __syncthreads();
#pragma unroll
  for (int rr = 0; rr < 32; rr += 8) {
    int j = j0 + ty + rr, i = i0 + tx;
    posQ[(size_t)(i >> 4) * 32768 + (size_t)(j >> 2) * 64 + (i & 15) * 4 +
         (j & 3)] = tile[tx][ty + rr];
  }
}

// ---------------- K1: LayerNorm (wave per row of 512), fp32 -> bf16 ----------
__global__ __launch_bounds__(256) void ln_kernel(
    const float* __restrict__ q, const float* __restrict__ k,
    const float* __restrict__ v, const float* __restrict__ w,
    const float* __restrict__ bia, bf16* __restrict__ qn,
    bf16* __restrict__ kn, bf16* __restrict__ vn) {
  int wv = threadIdx.x >> 6, lane = threadIdx.x & 63;
  int row = blockIdx.x * 4 + wv;  // 0..8191
  int which = blockIdx.y;
  const float* src = which == 0 ? q : (which == 1 ? k : v);
  bf16* dst        = which == 0 ? qn : (which == 1 ? kn : vn);

  f32x4 x0 = *(const f32x4*)(src + (size_t)row * Dm + lane * 8);
  f32x4 x1 = *(const f32x4*)(src + (size_t)row * Dm + lane * 8 + 4);
  float xf[8], s1 = 0.f, s2 = 0.f;
#pragma unroll
  for (int i = 0; i < 4; i++) { xf[i] = x0[i]; xf[4 + i] = x1[i]; }
#pragma unroll
  for (int i = 0; i < 8; i++) { s1 += xf[i]; s2 += xf[i] * xf[i]; }
#pragma unroll
  for (int m = 1; m < 64; m <<= 1) { s1 += __shfl_xor(s1, m, 64); s2 += __shfl_xor(s2, m, 64); }
  float mu = s1 * (1.0f / 512.0f);
  float var = s2 * (1.0f / 512.0f) - mu * mu;
  float rs = rsqrtf(var + 1e-5f);
  f32x4 w0 = *(const f32x4*)(w + lane * 8);
  f32x4 w1 = *(const f32x4*)(w + lane * 8 + 4);
  f32x4 b0 = *(const f32x4*)(bia + lane * 8);
  f32x4 b1 = *(const f32x4*)(bia + lane * 8 + 4);
  bfv8 o;
#pragma unroll
  for (int i = 0; i < 4; i++) {
    o[i]     = (bf16)((xf[i] - mu) * rs * w0[i] + b0[i]);
    o[4 + i] = (bf16)((xf[4 + i] - mu) * rs * w1[i] + b1[i]);
  }
  *(bfv8*)(dst + (size_t)row * Dm + lane * 8) = o;
}

// ---------------- shared GEMM body: C[m,n] = sum_k A[m,k]*W[n,k] + bias[n] ---
// A bf16 [M,512], W fp32 [N=512,512].  M=8192.
// mode 0: bf16 qh/kh [B,H,S,DK]; 1: bf16 vT [B,H,DK,S] with the PV k-perm
// applied inside each 32-key block; 2: fp32 out [M,512].
__device__ __forceinline__ void gemm_body(
    const bf16* __restrict__ A, const float* __restrict__ W,
    const float* __restrict__ bias, bf16* __restrict__ outb,
    float* __restrict__ outf, int mode, int m0, int n0) {
  __shared__ __align__(16) bf16 As[64][72];
  __shared__ __align__(16) bf16 Bs[64][72];
  int tid = threadIdx.x;
  int wv = tid >> 6, lane = tid & 63;
  int wm = (wv & 1) * 32, wn = (wv >> 1) * 32;
  int r16 = lane & 15, quad = lane >> 4;
  int lr = tid >> 2, sc = (tid & 3) * 16;

  f32x4 acc[2][2] = {};
  const bf16*  Ap = A + (size_t)(m0 + lr) * 512 + sc;
  const float* Wp = W + (size_t)(n0 + lr) * 512 + sc;

  for (int k0 = 0; k0 < 512; k0 += 64) {
    bfv8 a0 = *(const bfv8*)(Ap + k0);
    bfv8 a1 = *(const bfv8*)(Ap + k0 + 8);
    f32x4 w0 = *(const f32x4*)(Wp + k0);
    f32x4 w1 = *(const f32x4*)(Wp + k0 + 4);
    f32x4 w2 = *(const f32x4*)(Wp + k0 + 8);
    f32x4 w3 = *(const f32x4*)(Wp + k0 + 12);
    bfv8 bb0, bb1;
#pragma unroll
    for (int i = 0; i < 4; i++) {
      bb0[i] = (bf16)w0[i]; bb0[4 + i] = (bf16)w1[i];
      bb1[i] = (bf16)w2[i]; bb1[4 + i] = (bf16)w3[i];
    }
    __syncthreads();
    *(bfv8*)&As[lr][sc] = a0;  *(bfv8*)&As[lr][sc + 8] = a1;
    *(bfv8*)&Bs[lr][sc] = bb0; *(bfv8*)&Bs[lr][sc + 8] = bb1;
    __syncthreads();
#pragma unroll
    for (int kk = 0; kk < 2; kk++) {
      bfv8 af0 = *(const bfv8*)&As[wm + r16][kk * 32 + quad * 8];
      bfv8 af1 = *(const bfv8*)&As[wm + 16 + r16][kk * 32 + quad * 8];
      bfv8 bf0 = *(const bfv8*)&Bs[wn + r16][kk * 32 + quad * 8];
      bfv8 bf1 = *(const bfv8*)&Bs[wn + 16 + r16][kk * 32 + quad * 8];
      acc[0][0] = mfma16(af0, bf0, acc[0][0]);
      acc[0][1] = mfma16(af0, bf1, acc[0][1]);
      acc[1][0] = mfma16(af1, bf0, acc[1][0]);
      acc[1][1] = mfma16(af1, bf1, acc[1][1]);
    }
  }

#pragma unroll
  for (int nt = 0; nt < 2; nt++) {
    int n = n0 + wn + nt * 16 + r16;
    float bb = bias[n];
#pragma unroll
    for (int mt = 0; mt < 2; mt++) {
#pragma unroll
      for (int r = 0; r < 4; r++) {
        int m = m0 + wm + mt * 16 + quad * 4 + r;
        float o = acc[mt][nt][r] + bb;
        int bb_ = m >> 11, s = m & 2047, hh = n >> 6, dd = n & 63;
        if (mode == 0) {
          outb[(((size_t)(bb_ * Hh + hh)) * Sq + s) * 64 + dd] = (bf16)o;
        } else if (mode == 1) {
          // PV k-permutation inside each 32-key block:
          // position q*8 + b5*4 + r holds true key b5*16 + q*4 + r
          // (stays within the same 64-B line -> free).
          int local = s & 31;
          int pos = ((local >> 2) & 3) * 8 + (local >> 4) * 4 + (local & 3);
          int sp = (s & ~31) | pos;
          outb[(((size_t)(bb_ * Hh + hh)) * 64 + dd) * Sq + sp] = (bf16)o;
        } else {
          outf[(size_t)m * 512 + n] = o;
        }
      }
    }
  }
}

// ---- merged Q/K/V projection: blockIdx.z selects which projection ----------
__global__ __launch_bounds__(256) void gemm_proj(
    const bf16* __restrict__ qn, const bf16* __restrict__ kn,
    const bf16* __restrict__ vn, const float* __restrict__ Wq,
    const float* __restrict__ Wk, const float* __restrict__ Wv,
    const float* __restrict__ bq, const float* __restrict__ bk,
    const float* __restrict__ bv, bf16* __restrict__ qhp,
    bf16* __restrict__ khp, bf16* __restrict__ vhT) {
  int z = blockIdx.z;
  const bf16*  A    = z == 0 ? qn : (z == 1 ? kn : vn);
  const float* W    = z == 0 ? Wq : (z == 1 ? Wk : Wv);
  const float* bias = z == 0 ? bq : (z == 1 ? bk : bv);
  bf16*        outb = z == 0 ? qhp : (z == 1 ? khp : vhT);
  int mode = (z == 2) ? 1 : 0;
  gemm_body(A, W, bias, outb, nullptr, mode, blockIdx.x * 64, blockIdx.y * 64);
}

// ---- single GEMM (used for the output projection, mode 2) ------------------
__global__ __launch_bounds__(256) void gemm_bt(
    const bf16* __restrict__ A, const float* __restrict__ W,
    const float* __restrict__ bias, bf16* __restrict__ outb,
    float* __restrict__ outf, int mode) {
  gemm_body(A, W, bias, outb, outf, mode, blockIdx.x * 64, blockIdx.y * 64);
}

// ---------------- K3: attention: 16 q-rows x one (b,h) per block -------------
// 8 waves x 256 keys each.  Swapped QK^T: acc[t][r] = S[q=r16][key=c0+t*16+
// quad*4+r].  Softmax row-reduce = 2 shuffles; P -> PV entirely in registers
// (V is stored k-permuted to match the MFMA A-frag k slots); attn stores are
// per-lane f32x4 of 4 consecutive keys.  No Pbuf/Sst LDS at all.
__global__ __launch_bounds__(512, 4) void attn_kernel(
    const bf16* __restrict__ qh, const bf16* __restrict__ kh,
    const bf16* __restrict__ vT, const float* __restrict__ posQ,
    float* __restrict__ attn, bf16* __restrict__ xout) {
  __shared__ float smax[8][16];
  __shared__ float ssum[8][16];
  __shared__ __align__(16) float xred[8][16][64];   // 32 KB, epilogue only

  const int tid = threadIdx.x;
  const int wv = tid >> 6, lane = tid & 63;
  const int r16 = lane & 15, quad = lane >> 4;

  // bijective XCD swizzle: 4096 blocks, 8 XCDs, 512 per XCD.
  const int bid = blockIdx.x;
  const int nbid = (bid & 7) * 512 + (bid >> 3);
  const int bh = nbid >> 7;          // 0..31
  const int strip = nbid & 127;      // 0..127
  const int b = bh >> 3, h = bh & 7;
  const int r0 = strip * 16;
  const int c0 = wv * 256;           // wave's 256-key chunk

  const bf16* qbase = qh + (size_t)bh * Sq * 64;
  const bf16* kbase = kh + (size_t)bh * Sq * 64;
  const bf16* vbase = vT + (size_t)bh * 64 * Sq;
  const float* pbase = posQ + (size_t)strip * 32768;   // strip's 128-KB slab

  // Q as the B-operand: lane r16 = q-row, quad = k-group.
  bfv8 aq0 = *(const bfv8*)(qbase + (size_t)(r0 + r16) * 64 + quad * 8);
  bfv8 aq1 = *(const bfv8*)(qbase + (size_t)(r0 + r16) * 64 + 32 + quad * 8);

  // ---- phase 1: raw scores, K as the A-operand (swapped) ----
  f32x4 acc[16];
#pragma unroll
  for (int t = 0; t < 16; t++) {
    const bf16* kp = kbase + (size_t)(c0 + t * 16 + r16) * 64 + quad * 8;
    bfv8 kb0 = *(const bfv8*)kp;
    bfv8 kb1 = *(const bfv8*)(kp + 32);
    f32x4 z = {0.f, 0.f, 0.f, 0.f};
    z = mfma16(kb0, aq0, z);
    z = mfma16(kb1, aq1, z);
    acc[t] = z;   // acc[t][r]: q = r16, key = c0 + t*16 + quad*4 + r
  }

  // ---- phase 2: s = s/8 + pos; per-row softmax (row = r16, lane-local) ----
  float mx = -1e30f;
#pragma unroll
  for (int t = 0; t < 16; t++) {
    f32x4 pk = *(const f32x4*)(pbase + (size_t)((c0 >> 2) + t * 4 + quad) * 64 +
                               r16 * 4);
#pragma unroll
    for (int r = 0; r < 4; r++) {
      float s = acc[t][r] * 0.125f + pk[r];
      acc[t][r] = s;
      mx = fmaxf(mx, s);
    }
  }
  mx = fmaxf(mx, __shfl_xor(mx, 16, 64));
  mx = fmaxf(mx, __shfl_xor(mx, 32, 64));

  float sm = 0.f;
#pragma unroll
  for (int t = 0; t < 16; t++)
#pragma unroll
    for (int r = 0; r < 4; r++) {
      float e = __expf(acc[t][r] - mx);
      acc[t][r] = e;
      sm += e;
    }
  sm += __shfl_xor(sm, 16, 64);
  sm += __shfl_xor(sm, 32, 64);

  if (quad == 0) {
    smax[wv][r16] = mx;
    ssum[wv][r16] = sm;
  }
  __syncthreads();

  float M = smax[0][r16];
#pragma unroll
  for (int w = 1; w < 8; w++) M = fmaxf(M, smax[w][r16]);
  float S = 0.f;
#pragma unroll
  for (int w = 0; w < 8; w++) S += ssum[w][r16] * __expf(smax[w][r16] - M);
  float comb = __expf(mx - M) / S;   // p = e * comb == exp(x - M) / S

  // ---- phase 3: per 32-key slice: f32x4 attn store + in-register PV ----
  float* arow = attn + ((size_t)bh * Sq + r0 + r16) * Sq;
  f32x4 xacc[4] = {};
#pragma unroll
  for (int ks = 0; ks < 8; ks++) {
    f32x4 p0, p1;
#pragma unroll
    for (int r = 0; r < 4; r++) {
      p0[r] = acc[2 * ks][r] * comb;
      p1[r] = acc[2 * ks + 1][r] * comb;
    }
    int key0 = c0 + ks * 32;
    *(f32x4*)(arow + key0 + quad * 4) = p0;        // 16 rows x 64 B / instr;
    *(f32x4*)(arow + key0 + 16 + quad * 4) = p1;   // pair completes the line
    bfv8 pa;
#pragma unroll
    for (int r = 0; r < 4; r++) { pa[r] = (bf16)p0[r]; pa[4 + r] = (bf16)p1[r]; }
    // V stored k-permuted: position quad*8+j holds true key
    // key0 + (j>=4)*16 + quad*4 + (j&3) == exactly pa's k slots.
#pragma unroll
    for (int nt = 0; nt < 4; nt++) {
      bfv8 bvv = *(const bfv8*)(vbase + (size_t)(nt * 16 + r16) * Sq + key0 + quad * 8);
      xacc[nt] = mfma16(pa, bvv, xacc[nt]);
    }
  }
  // xacc[nt][r] = x[q = quad*4 + r][d = nt*16 + r16]  (same as before)

  // ---- cross-wave x reduction -> x[B,S,D] (bf16 for the final GEMM) ----
#pragma unroll
  for (int nt = 0; nt < 4; nt++)
#pragma unroll
    for (int r = 0; r < 4; r++)
      xred[wv][quad * 4 + r][nt * 16 + r16] = xacc[nt][r];
  __syncthreads();
  {
    int row = tid >> 5, d2 = (tid & 31) * 2;   // 512 thr: 16 rows x 32 pairs
    f32x2 s = {0.f, 0.f};
#pragma unroll
    for (int w = 0; w < 8; w++) s += *(const f32x2*)&xred[w][row][d2];
    bfv2 o;
    o[0] = (bf16)s[0];
    o[1] = (bf16)s[1];
    *(bfv2*)(xout + ((size_t)(b * Sq + r0 + row)) * 512 + h * 64 + d2) = o;
  }
}

// ---------------------------------------------------------------------------
extern "C" void kernel_launch(void* const* d_in, const int* in_sizes, int n_in,
                              void* d_out, int out_size, void* d_ws,
                              size_t ws_size, hipStream_t stream) {
  const float* q    = (const float*)d_in[0];
  const float* k    = (const float*)d_in[1];
  const float* v    = (const float*)d_in[2];
  const int*   mask = (const int*)d_in[3];
  const float* pos  = (const float*)d_in[4];
  const float* lnw  = (const float*)d_in[5];
  const float* lnb  = (const float*)d_in[6];
  const float* Wq   = (const float*)d_in[7];
  const float* bq   = (const float*)d_in[8];
  const float* Wk   = (const float*)d_in[9];
  const float* bk   = (const float*)d_in[10];
  const float* Wv   = (const float*)d_in[11];
  const float* bv   = (const float*)d_in[12];
  const float* Wo   = (const float*)d_in[13];
  const float* bo   = (const float*)d_in[14];

  const size_t NE = (size_t)Bb * Sq * Dm;  // 4,194,304 (== S*S)
  if (ws_size < 64ull * 1024 * 1024) return;  // need exactly 64 MiB scratch

  // ws layout (64 MiB total):
  //   [ 0,16) MiB  posQ  fp32 [S/16][S/4][16][4]  (strip-tiled masked pos)
  //   [16,24) MiB  qn    bf16 [8192,512]   (aliased by xbuf after use)
  //   [24,32) MiB  kn    bf16
  //   [32,40) MiB  vn    bf16
  //   [40,48) MiB  qhp   bf16 [B,H,S,DK]
  //   [48,56) MiB  khp   bf16 [B,H,S,DK]
  //   [56,64) MiB  vhT   bf16 [B,H,DK,S]  (k-permuted within 32-key blocks)
  char* wsb = (char*)d_ws;
  float* posQ = (float*)wsb;
  bf16* qn   = (bf16*)(wsb + 16ull * 1024 * 1024);
  bf16* kn   = (bf16*)(wsb + 24ull * 1024 * 1024);
  bf16* vn   = (bf16*)(wsb + 32ull * 1024 * 1024);
  bf16* qhp  = (bf16*)(wsb + 40ull * 1024 * 1024);
  bf16* khp  = (bf16*)(wsb + 48ull * 1024 * 1024);
  bf16* vhT  = (bf16*)(wsb + 56ull * 1024 * 1024);
  bf16* xbuf = qn;  // qn is dead once the Q projection GEMM has run

  float* out  = (float*)d_out;
  float* attn = out + NE;

  posQ_kernel<<<dim3(Sq / 32, Sq / 32), 256, 0, stream>>>(pos, mask, posQ);
  ln_kernel<<<dim3(BS / 4, 3), 256, 0, stream>>>(q, k, v, lnw, lnb, qn, kn, vn);
  gemm_proj<<<dim3(BS / 64, Dm / 64, 3), 256, 0, stream>>>(
      qn, kn, vn, Wq, Wk, Wv, bq, bk, bv, qhp, khp, vhT);
  attn_kernel<<<dim3((Sq / 16) * Hh * Bb), 512, 0, stream>>>(qhp, khp, vhT,
                                                             posQ, attn, xbuf);
  gemm_bt<<<dim3(BS / 64, Dm / 64), 256, 0, stream>>>(xbuf, Wo, bo, nullptr, out, 2);
}